// Round 18
// baseline (150.203 us; speedup 1.0000x reference)
//
#include <hip/hip_runtime.h>
#include <math.h>

typedef __attribute__((ext_vector_type(8))) short short8;
typedef _Float16 half8 __attribute__((ext_vector_type(8)));
typedef __attribute__((ext_vector_type(4))) float f32x4;
typedef __attribute__((ext_vector_type(2))) uint uint2v;
typedef unsigned int uint;
typedef unsigned short ushort;

#define N_PTS 200000
#define N_PAD 200064          // 1563 * 128 ; 12504 row-tiles of 16
#define NBLK  1563
#define YST   168             // k3 LDS y-tile row stride (shorts)
#define ZK    (-18.033688011112043f)   // -12.5 * log2(e)
#define C2K   (36.067376022224086f)    // -2 * ZK

// Tiled layouts (MFMA-fragment order):
//   FT[(rt*5 + kc)*512 + l*8 + e]  = feat[rt*16 + (l&15)][kc*32 + (l>>4)*8 + e]
//   WTt[(tc*5 + kc)*512 + l*8 + e] = W[tc*16 + (l&15)][kc*32 + (l>>4)*8 + e]

// ---------------- ws layout (bytes) ----------------
#define FEAT_OFF  0ull
#define WT1_OFF   118437888ull
#define WT2_OFF   118483968ull      // contiguous after WT1 (46080 B each)
#define KERN2_OFF 118530048ull
#define WSUM_OFF  118534144ull
#define L3H_OFF   118534528ull
#define L4H_OFF   118538624ull
#define GSUM_OFF  118546816ull
#define GSQ_OFF   118547456ull

__device__ inline ushort f2h(float x) {
    return __builtin_bit_cast(ushort, (_Float16)x);
}
__device__ inline uint pack2h(float a, float b) {   // v_cvt_pkrtz_f16_f32
    return __builtin_bit_cast(uint, __builtin_amdgcn_cvt_pkrtz(a, b));
}

// ============ K0: all tables (91 blocks); W1/W2 in tiled order ============
__global__ void sdes_k0_setup(const float* __restrict__ conv_w, const float* __restrict__ l3w,
                              const float* __restrict__ l4w, const float* __restrict__ theta,
                              const float* __restrict__ phi, const float* __restrict__ c1w,
                              const float* __restrict__ c2w,
                              float* wsumT, ushort* l3h, ushort* l4h, float* kern2,
                              ushort* WT1t, ushort* WT2t, float* gsum, float* gsq)
{
    const int t = threadIdx.x, b = blockIdx.x;
    if (b == 90) {              // small tables
        for (int i = t; i < 96; i += 256) {
            int k = i >> 5, o = i & 31;
            wsumT[k * 32 + o] = conv_w[o * 6 + k] + conv_w[o * 6 + k + 3];
        }
        for (int i = t; i < 2048; i += 256) l3h[i] = f2h(l3w[i]);
        for (int i = t; i < 4096; i += 256) l4h[i] = f2h(l4w[i]);
        int m = t >> 2, bb = t & 3;
        float th = theta[m * 4 + bb], ph = phi[m * 4 + bb];
        float st = sinf(th), ct = cosf(th), sp = sinf(ph), cp = cosf(ph);
        kern2[m * 16 + bb * 4 + 0] = st * sp * C2K;
        kern2[m * 16 + bb * 4 + 1] = st * cp * C2K;
        kern2[m * 16 + bb * 4 + 2] = ct * C2K;
        kern2[m * 16 + bb * 4 + 3] = 0.f;
        return;
    }
    if (b == 0 && t < 160) { gsum[t] = 0.f; gsq[t] = 0.f; }
    int i = b * 256 + t;
    if (i >= 144 * 160) return;
    int e = i & 7, l = (i >> 3) & 63, rem = i >> 9;
    int kc = rem % 5, tc = rem / 5;
    int n = tc * 16 + (l & 15);
    int k = kc * 32 + (l >> 4) * 8 + e;
    float v = 0.f;
    if (n < 131) {
        if (k < 64)       v = c1w[n * 131 + 3 + k];
        else if (k < 128) v = c1w[n * 131 + 67 + (k - 64)];
        else if (k < 131) v = c1w[n * 131 + (k - 128)];
    }
    WT1t[i] = f2h(v);
    float v2 = (n < 131 && k < 131) ? c2w[n * 131 + k] : 0.f;
    WT2t[i] = f2h(v2);
}

// ============ K1ab: merged MLP (MFMA) + kernel-correlation -> tiled feat ============
// r18: r13 structure, z split 8 threads/point (1024 thr, 1 qq-group each):
// halves the per-thread serial chain again and reaches 32 waves/CU (8/SIMD max).
#define FST 40
#define W3T 40
#define W4T 72
__global__ __launch_bounds__(1024) void sdes_k1ab(
    const float* __restrict__ corner, const float* __restrict__ conv_b,
    const float* __restrict__ wsumT, const ushort* __restrict__ l3h,
    const float* __restrict__ l3b, const ushort* __restrict__ l4h,
    const float* __restrict__ l4b,
    const float* __restrict__ normal, const int* __restrict__ neigh,
    const float* __restrict__ kern2g, ushort* __restrict__ feat)
{
    __shared__ __align__(16) ushort frcS[128 * FST];
    __shared__ __align__(16) ushort hS[128 * 64];
    __shared__ __align__(16) ushort w3S[64 * W3T];
    __shared__ __align__(16) ushort w4S[64 * W4T];
    __shared__ float wsL[96], cbL[32], b3L[64], b4L[64];
    const int t = threadIdx.x;

    // ---- stage k1a tables ----
    for (int i = t; i < 96; i += 1024) wsL[i] = wsumT[i];
    for (int i = t; i < 32; i += 1024) cbL[i] = conv_b[i];
    for (int i = t; i < 64; i += 1024) { b3L[i] = l3b[i]; b4L[i] = l4b[i]; }
    for (int i = t; i < 256; i += 1024) {
        int c = i >> 2, kc = i & 3;
        *(uint4*)&w3S[c * W3T + kc * 8] = *(const uint4*)&l3h[c * 32 + kc * 8];
    }
    for (int i = t; i < 512; i += 1024) {
        int c = i >> 3, kc = i & 7;
        *(uint4*)&w4S[c * W4T + kc * 8] = *(const uint4*)&l4h[c * 64 + kc * 8];
    }
    __syncthreads();

    // ---- k1a per-point conv (threads 0..127) ----
    if (t < 128) {
        int row = blockIdx.x * 128 + t;
        int p = row < N_PTS ? row : N_PTS - 1;
        const float* cp = corner + (size_t)p * 9;
        float c0 = cp[0], c1 = cp[1], c2 = cp[2], c3 = cp[3], c4 = cp[4],
              c5 = cp[5], c6 = cp[6], c7 = cp[7], c8 = cp[8];
        float mp0 = (c0 + c3 + c6) * (1.f / 3.f);
        float mp1 = (c1 + c4 + c7) * (1.f / 3.f);
        float mp2 = (c2 + c5 + c8) * (1.f / 3.f);
        #pragma unroll
        for (int o = 0; o < 32; o += 2) {
            float f0 = fmaf(mp0, wsL[o], fmaf(mp1, wsL[32 + o], fmaf(mp2, wsL[64 + o], cbL[o])));
            float f1 = fmaf(mp0, wsL[o+1], fmaf(mp1, wsL[33 + o], fmaf(mp2, wsL[65 + o], cbL[o+1])));
            *(uint*)&frcS[t * FST + o] = pack2h(f0, f1);
        }
    }

    // ---- k1b body (all 1024 threads, 8 threads/point; kern2 via s_load) ----
    {
        const int g  = t >> 7;                 // 0..7: (tt = g&1) m-half, (qq = g>>1) qq-group
        const int tt = g & 1;
        const int qq = g >> 1;                 // 0..3
        const int pi = t & 127;
        const int p0 = blockIdx.x * 128 + pi;
        const int p = p0 < N_PTS ? p0 : N_PTS - 1;
        const int rt = p0 >> 4, pl = p0 & 15;
        float f0[4], f1[4], f2v[4];
        f0[0] = normal[(size_t)p * 3 + 0]; f1[0] = normal[(size_t)p * 3 + 1]; f2v[0] = normal[(size_t)p * 3 + 2];
        #pragma unroll
        for (int a = 1; a < 4; ++a) {
            int nb = neigh[(size_t)p * 3 + (a - 1)];
            f0[a] = normal[(size_t)nb * 3 + 0];
            f1[a] = normal[(size_t)nb * 3 + 1];
            f2v[a] = normal[(size_t)nb * 3 + 2];
        }
        float base[4];
        #pragma unroll
        for (int a = 0; a < 4; ++a)
            base[a] = (f0[a]*f0[a] + f1[a]*f1[a] + f2v[a]*f2v[a] + 1.0f) * ZK;
        const size_t tbase = ((size_t)(rt * 5 + 2 + tt)) * 512;
        {
            float zv[8];
            #pragma unroll
            for (int mm = 0; mm < 8; ++mm) {
                int m = (tt * 4 + qq) * 8 + mm;
                const float* kp = kern2g + m * 16;   // lane-invariant -> s_load (SGPR)
                float a0 = 0.f, a1 = 0.f, a2 = 0.f, a3 = 0.f;
                #pragma unroll
                for (int b = 0; b < 4; ++b) {
                    float kx = kp[b * 4 + 0], ky = kp[b * 4 + 1], kz = kp[b * 4 + 2];
                    a0 += __builtin_amdgcn_exp2f(fmaf(f0[0], kx, fmaf(f1[0], ky, fmaf(f2v[0], kz, base[0]))));
                    a1 += __builtin_amdgcn_exp2f(fmaf(f0[1], kx, fmaf(f1[1], ky, fmaf(f2v[1], kz, base[1]))));
                    a2 += __builtin_amdgcn_exp2f(fmaf(f0[2], kx, fmaf(f1[2], ky, fmaf(f2v[2], kz, base[2]))));
                    a3 += __builtin_amdgcn_exp2f(fmaf(f0[3], kx, fmaf(f1[3], ky, fmaf(f2v[3], kz, base[3]))));
                }
                zv[mm] = ((a0 + a1) + (a2 + a3)) * (1.f / 16.f);
            }
            uint4 v;
            v.x = pack2h(zv[0], zv[1]); v.y = pack2h(zv[2], zv[3]);
            v.z = pack2h(zv[4], zv[5]); v.w = pack2h(zv[6], zv[7]);
            *(uint4*)(feat + tbase + (pl + 16 * qq) * 8) = v;
        }
        {   // kc4 tile: rows pl+16*g for g 0..3; g==0 carries the normal, 1..3 zeros
            size_t base4 = ((size_t)(rt * 5 + 4)) * 512;
            if (g == 0) {
                uint4 v;
                v.x = pack2h(f0[0], f1[0]); v.y = pack2h(f2v[0], 0.f); v.z = 0u; v.w = 0u;
                *(uint4*)(feat + base4 + pl * 8) = v;
            } else if (g < 4) {
                const uint4 zz = {0u, 0u, 0u, 0u};
                *(uint4*)(feat + base4 + (pl + 16 * g) * 8) = zz;
            }
        }
    }
    __syncthreads();

    // ---- k1a MFMA layers (waves 0,1 only) ----
    const int lane = t & 63, w = t >> 6;
    const int rlo = lane & 15, kg = lane >> 4;
    const f32x4 z4 = {0.f, 0.f, 0.f, 0.f};

    if (w < 2) {   // layer 3: h[point][col] -> swizzled hS
        const int rbase = w * 64;
        half8 af[4], bf[4];
        #pragma unroll
        for (int rt = 0; rt < 4; ++rt)
            af[rt] = *(const half8*)&frcS[(rbase + rt * 16 + rlo) * FST + kg * 8];
        #pragma unroll
        for (int tc = 0; tc < 4; ++tc)
            bf[tc] = *(const half8*)&w3S[(tc * 16 + rlo) * W3T + kg * 8];
        #pragma unroll
        for (int rt = 0; rt < 4; ++rt) {
            #pragma unroll
            for (int tc = 0; tc < 4; ++tc) {
                f32x4 acc = __builtin_amdgcn_mfma_f32_16x16x32_f16(af[rt], bf[tc], z4, 0, 0, 0);
                int col = tc * 16 + rlo;
                float bias = b3L[col];
                #pragma unroll
                for (int r = 0; r < 4; ++r) {
                    int hrow = rbase + rt * 16 + kg * 4 + r;
                    float v = fmaxf(acc[r] + bias, 0.f);
                    int sc = (((col >> 3) ^ (hrow & 7)) << 3) | (col & 7);
                    hS[hrow * 64 + sc] = f2h(v);
                }
            }
        }
    }
    __syncthreads();

    if (w < 2) {   // layer 4 SWAPPED: acc = mfma(W4_frag, h_frag) -> D[xcol][point]
        const int rbase = w * 64;
        f32x4 acc4[4][4];
        #pragma unroll
        for (int pt = 0; pt < 4; ++pt)
            #pragma unroll
            for (int tc = 0; tc < 4; ++tc) acc4[pt][tc] = z4;
        #pragma unroll
        for (int ks = 0; ks < 2; ++ks) {
            half8 af[4], bf[4];
            #pragma unroll
            for (int pt = 0; pt < 4; ++pt) {
                int row = rbase + pt * 16 + rlo;
                int blk = (ks * 4 + kg) ^ (rlo & 7);
                af[pt] = *(const half8*)&hS[row * 64 + blk * 8];
            }
            #pragma unroll
            for (int tc = 0; tc < 4; ++tc)
                bf[tc] = *(const half8*)&w4S[(tc * 16 + rlo) * W4T + ks * 32 + kg * 8];
            #pragma unroll
            for (int pt = 0; pt < 4; ++pt)
                #pragma unroll
                for (int tc = 0; tc < 4; ++tc)
                    acc4[pt][tc] = __builtin_amdgcn_mfma_f32_16x16x32_f16(bf[tc], af[pt], acc4[pt][tc], 0, 0, 0);
        }
        #pragma unroll
        for (int pt = 0; pt < 4; ++pt) {
            int rtg = blockIdx.x * 8 + w * 4 + pt;
            #pragma unroll
            for (int tc = 0; tc < 4; ++tc) {
                int xb = tc * 16 + kg * 4;
                float v0 = acc4[pt][tc][0] + b4L[xb + 0];
                float v1 = acc4[pt][tc][1] + b4L[xb + 1];
                float v2 = acc4[pt][tc][2] + b4L[xb + 2];
                float v3 = acc4[pt][tc][3] + b4L[xb + 3];
                uint2v st; st.x = pack2h(v0, v1); st.y = pack2h(v2, v3);
                int kc = tc >> 1;
                int l = rlo + 16 * ((2 * tc + (kg >> 1)) & 3);
                size_t off = ((size_t)(rtg * 5 + kc)) * 512 + l * 8 + (kg & 1) * 4;
                *(uint2v*)(feat + off) = st;
            }
        }
    }
}

// ============ K2s: PERSISTENT stats GEMM1; 256 blocks x 1024 thr (16 waves, 4/SIMD) ====
__global__ __launch_bounds__(1024, 4) void sdes_k2_stats(
    const ushort* __restrict__ FT, const ushort* __restrict__ WT1t,
    const float* __restrict__ c1b, float* __restrict__ gsum, float* __restrict__ gsq)
{
    __shared__ __align__(16) ushort W1s[45 * 512];     // 46080 B
    __shared__ float sS[144], sQ[144];
    const int t = threadIdx.x;
    const int lane = t & 63, wv = t >> 6;
    const int b = blockIdx.x;
    const int s = b * 16 + wv;                         // 4096 slots
    const int rlo = lane & 15, kg = lane >> 4;

    // balanced contiguous tile range: 12504 = 4096*3 + 216
    const int cnt = 3 + ((wv == 0 && b < 216) ? 1 : 0);
    const int start = 3 * s + (b < 216 ? b : 216) + ((b < 216 && wv > 0) ? 1 : 0);

    // first-tile FT prefetch (rides under the W1 staging)
    half8 afA[5], afB[5];
    #pragma unroll
    for (int kc = 0; kc < 5; ++kc)
        afA[kc] = *(const half8*)(FT + ((size_t)start * 5 + kc) * 512 + lane * 8);

    for (int i = t; i < 2880; i += 1024) ((uint4*)W1s)[i] = ((const uint4*)WT1t)[i];
    if (t < 144) { sS[t] = 0.f; sQ[t] = 0.f; }
    __syncthreads();

    float sreg[9], qreg[9], bL[9];
    #pragma unroll
    for (int tc = 0; tc < 9; ++tc) {
        sreg[tc] = 0.f; qreg[tc] = 0.f;
        int n = tc * 16 + rlo;
        bL[tc] = (n < 131) ? c1b[n] : 0.f;
    }

    for (int it = 0; it < cnt; ++it) {
        const int p = start + it;
        f32x4 acc[9];
        #pragma unroll
        for (int tc = 0; tc < 9; ++tc) acc[tc] = (f32x4){0.f, 0.f, 0.f, 0.f};
        #pragma unroll
        for (int kc = 0; kc < 5; ++kc) {
            #pragma unroll
            for (int tc = 0; tc < 9; ++tc) {
                half8 bw = *(const half8*)(W1s + (tc * 5 + kc) * 512 + lane * 8);
                acc[tc] = __builtin_amdgcn_mfma_f32_16x16x32_f16(afA[kc], bw, acc[tc], 0, 0, 0);
            }
        }
        if (it + 1 < cnt) {
            #pragma unroll
            for (int kc = 0; kc < 5; ++kc)
                afB[kc] = *(const half8*)(FT + ((size_t)(p + 1) * 5 + kc) * 512 + lane * 8);
            __builtin_amdgcn_sched_barrier(0);   // pin prefetch issue here
        }
        const int row0 = p * 16;
        #pragma unroll
        for (int tc = 0; tc < 9; ++tc) {
            float b0 = bL[tc];
            #pragma unroll
            for (int r = 0; r < 4; ++r) {
                int grow = row0 + kg * 4 + r;
                if (grow < N_PTS) {
                    float v = acc[tc][r] + b0;
                    sreg[tc] += v;
                    qreg[tc] = fmaf(v, v, qreg[tc]);
                }
            }
        }
        #pragma unroll
        for (int kc = 0; kc < 5; ++kc) afA[kc] = afB[kc];
    }

    #pragma unroll
    for (int tc = 0; tc < 9; ++tc) {
        float sv = sreg[tc], qv = qreg[tc];
        sv += __shfl_xor(sv, 16);  sv += __shfl_xor(sv, 32);
        qv += __shfl_xor(qv, 16);  qv += __shfl_xor(qv, 32);
        if (lane < 16) {
            int n = tc * 16 + rlo;
            atomicAdd(&sS[n], sv); atomicAdd(&sQ[n], qv);
        }
    }
    __syncthreads();
    if (t < 144) { atomicAdd(&gsum[t], sS[t]); atomicAdd(&gsq[t], sQ[t]); }
}

// ============ K3f: PERSISTENT fused GEMM1 -> bn/relu -> slab -> GEMM2 ============
// 256 blocks x 768 threads (12 waves, 3/SIMD). Ws staged + BN finalized ONCE per
// block; balanced contiguous pair ranges; double-buffered FT prefetch.
// Phase B SWAPPED (D[chan][point]) -> lane owns 4 CONSECUTIVE chans of one row
// -> single cached float4 store per tc (wave covers 16 rows x 64B full segments).
__global__ __launch_bounds__(768, 3) void sdes_k3_fused(
    const ushort* __restrict__ FT, const ushort* __restrict__ WT1t,
    const ushort* __restrict__ WT2t, const float* __restrict__ c1b,
    const float* __restrict__ gsum, const float* __restrict__ gsq,
    const float* __restrict__ bng, const float* __restrict__ bnb,
    const float* __restrict__ c2b, float* __restrict__ out)
{
    __shared__ __align__(16) ushort Ws[2 * 45 * 512];   // 92160 B: W1 [0..23039], W2 [23040..]
    __shared__ __align__(16) ushort yS[192 * YST];      // 12 waves x 16 rows x 168 = 64512 B
    __shared__ __align__(16) float scL[160], shL[160], b1L[160], c2L[160];
    const int t = threadIdx.x;
    const int lane = t & 63, wv = t >> 6;
    const int rlo = lane & 15, kg = lane >> 4;
    const int b = blockIdx.x;
    const int s = b * 12 + wv;                          // 3072 slots

    // balanced contiguous pair range: 6252 = 3072*2 + 108 (extra -> wv0 of b<108)
    const int cnt = 2 + ((wv == 0 && b < 108) ? 1 : 0);
    const int start = 2 * s + (b < 108 ? b : 108) + ((b < 108 && wv > 0) ? 1 : 0);

    // ---- first-pair FT prefetch, issued BEFORE staging (rides under L2 staging) ----
    half8 afA[5][2], afB[5][2];
    #pragma unroll
    for (int kc = 0; kc < 5; ++kc)
        #pragma unroll
        for (int pt = 0; pt < 2; ++pt)
            afA[kc][pt] = *(const half8*)(FT + ((size_t)(start * 2 + pt) * 5 + kc) * 512 + lane * 8);

    // ---- stage both weight matrices into LDS (92 KB, ONCE per block) ----
    for (int i = t; i < 5760; i += 768) ((uint4*)Ws)[i] = ((const uint4*)WT1t)[i];

    // ---- BN finalize (once per block, 131 lanes) ----
    if (t < 160) {
        float sc = 0.f, sh = 0.f, bb = 0.f, c2 = 0.f;
        if (t < 131) {
            float mu = gsum[t] * (1.f / 200000.f);
            float var = gsq[t] * (1.f / 200000.f) - mu * mu;
            sc = bng[t] / sqrtf(var + 1e-5f);
            sh = bnb[t] - mu * sc;
            bb = c1b[t]; c2 = c2b[t];
        }
        scL[t] = sc; shL[t] = sh; b1L[t] = bb; c2L[t] = c2;
    }
    __syncthreads();

    const half8 hz = {0, 0, 0, 0, 0, 0, 0, 0};
    ushort* slab = yS + wv * 16 * YST;      // this wave's 16-row slab (reused per pt/iter)

    for (int it = 0; it < cnt; ++it) {
        const int p = start + it;

        // ---- Phase A: y = feat @ W1^T (D[point][chan]); W1 from LDS ----
        f32x4 acc[2][9];
        #pragma unroll
        for (int pt = 0; pt < 2; ++pt)
            #pragma unroll
            for (int tc = 0; tc < 9; ++tc) acc[pt][tc] = (f32x4){0.f, 0.f, 0.f, 0.f};
        #pragma unroll
        for (int kc = 0; kc < 5; ++kc) {
            #pragma unroll
            for (int tc = 0; tc < 9; ++tc) {
                half8 bw = *(const half8*)(Ws + (tc * 5 + kc) * 512 + lane * 8);
                #pragma unroll
                for (int pt = 0; pt < 2; ++pt)
                    acc[pt][tc] = __builtin_amdgcn_mfma_f32_16x16x32_f16(afA[kc][pt], bw, acc[pt][tc], 0, 0, 0);
            }
        }

        // ---- prefetch next pair's FT fragments (pinned; hides under phase B) ----
        if (it + 1 < cnt) {
            #pragma unroll
            for (int kc = 0; kc < 5; ++kc)
                #pragma unroll
                for (int pt = 0; pt < 2; ++pt)
                    afB[kc][pt] = *(const half8*)(FT + ((size_t)((p + 1) * 2 + pt) * 5 + kc) * 512 + lane * 8);
            __builtin_amdgcn_sched_barrier(0);
        }

        const int row0 = p * 32;
        #pragma unroll
        for (int pt = 0; pt < 2; ++pt) {
            // ---- bias + bn + relu -> slab (16 rows x 144 chans; chans>=131 exact 0) ----
            #pragma unroll
            for (int tc = 0; tc < 9; ++tc) {
                int n = tc * 16 + rlo;
                float sc = scL[n], sh = shL[n], bb = b1L[n];
                #pragma unroll
                for (int r = 0; r < 4; ++r) {
                    float v = fmaxf(fmaf(acc[pt][tc][r] + bb, sc, sh), 0.f);
                    slab[(kg * 4 + r) * YST + n] = f2h(v);
                }
            }
            // same-wave DS ordering: reads below see this pt's writes.

            // ---- Phase B SWAPPED: out = y_relu @ W2^T, D[chan][point] ----
            f32x4 acc2[9];
            #pragma unroll
            for (int tc = 0; tc < 9; ++tc) acc2[tc] = (f32x4){0.f, 0.f, 0.f, 0.f};
            #pragma unroll
            for (int kc2 = 0; kc2 < 5; ++kc2) {
                bool vld = (kc2 < 4) || (kg < 2);
                half8 af2 = vld ? *(const half8*)&slab[rlo * YST + kc2 * 32 + kg * 8] : hz;
                #pragma unroll
                for (int tc = 0; tc < 9; ++tc) {
                    half8 bw = *(const half8*)(Ws + 23040 + (tc * 5 + kc2) * 512 + lane * 8);
                    acc2[tc] = __builtin_amdgcn_mfma_f32_16x16x32_f16(bw, af2, acc2[tc], 0, 0, 0);
                }
            }
            // ---- epilogue: lane owns point=row0+pt*16+rlo, chans tc*16+kg*4+0..3
            //      single cached float4 store per tc (4B-aligned rows OK on gfx950) ----
            const int prow = row0 + pt * 16 + rlo;
            if (prow < N_PTS) {
                float* op = out + (size_t)prow * 131;
                #pragma unroll
                for (int tc = 0; tc < 8; ++tc) {
                    const int c0 = tc * 16 + kg * 4;
                    f32x4 vv = acc2[tc] + *(const f32x4*)&c2L[c0];
                    __builtin_memcpy(op + c0, &vv, 16);   // global_store_dwordx4, align 4
                }
                if (kg == 0) {   // chans 128..130
                    op[128] = acc2[8][0] + c2L[128];
                    op[129] = acc2[8][1] + c2L[129];
                    op[130] = acc2[8][2] + c2L[130];
                }
            }
        }

        // ---- rotate double buffer ----
        #pragma unroll
        for (int kc = 0; kc < 5; ++kc)
            #pragma unroll
            for (int pt = 0; pt < 2; ++pt)
                afA[kc][pt] = afB[kc][pt];
    }
}

extern "C" void kernel_launch(void* const* d_in, const int* in_sizes, int n_in,
                              void* d_out, int out_size, void* d_ws, size_t ws_size,
                              hipStream_t stream) {
    const float* corner = (const float*)d_in[0];
    const float* normal = (const float*)d_in[1];
    const int*   neigh  = (const int*)d_in[2];
    const float* conv_w = (const float*)d_in[3];
    const float* conv_b = (const float*)d_in[4];
    const float* l3_w   = (const float*)d_in[5];
    const float* l3_b   = (const float*)d_in[6];
    const float* l4_w   = (const float*)d_in[7];
    const float* l4_b   = (const float*)d_in[8];
    const float* theta  = (const float*)d_in[9];
    const float* phi    = (const float*)d_in[10];
    const float* c1_w   = (const float*)d_in[11];
    const float* c1_b   = (const float*)d_in[12];
    const float* c2_w   = (const float*)d_in[13];
    const float* c2_b   = (const float*)d_in[14];
    const float* bn_g   = (const float*)d_in[15];
    const float* bn_b   = (const float*)d_in[16];

    char* ws = (char*)d_ws;
    ushort* feat  = (ushort*)(ws + FEAT_OFF);
    ushort* WT1t  = (ushort*)(ws + WT1_OFF);
    ushort* WT2t  = (ushort*)(ws + WT2_OFF);
    float*  kern2 = (float*)(ws + KERN2_OFF);
    float*  wsumT = (float*)(ws + WSUM_OFF);
    ushort* l3h   = (ushort*)(ws + L3H_OFF);
    ushort* l4h   = (ushort*)(ws + L4H_OFF);
    float*  gsum  = (float*)(ws + GSUM_OFF);
    float*  gsq   = (float*)(ws + GSQ_OFF);

    sdes_k0_setup<<<91, 256, 0, stream>>>(conv_w, l3_w, l4_w, theta, phi, c1_w, c2_w,
                                          wsumT, l3h, l4h, kern2, WT1t, WT2t, gsum, gsq);
    sdes_k1ab<<<NBLK, 1024, 0, stream>>>(corner, conv_b, wsumT, l3h, l3_b, l4h, l4_b,
                                         normal, neigh, kern2, feat);
    sdes_k2_stats<<<256, 1024, 0, stream>>>(feat, WT1t, c1_b, gsum, gsq);
    sdes_k3_fused<<<256, 768, 0, stream>>>(feat, WT1t, WT2t, c1_b, gsum, gsq,
                                           bn_g, bn_b, c2_b, (float*)d_out);
}

// Round 19
// 128.726 us; speedup vs baseline: 1.1668x; 1.1668x over previous
//
#include <hip/hip_runtime.h>
#include <math.h>

typedef __attribute__((ext_vector_type(8))) short short8;
typedef _Float16 half8 __attribute__((ext_vector_type(8)));
typedef __attribute__((ext_vector_type(4))) float f32x4;
typedef __attribute__((ext_vector_type(2))) uint uint2v;
typedef unsigned int uint;
typedef unsigned short ushort;

#define N_PTS 200000
#define N_PAD 200064          // 1563 * 128 ; 12504 row-tiles of 16
#define NBLK  1563
#define YST   168             // k3 LDS y-tile row stride (shorts)
#define ZK    (-18.033688011112043f)   // -12.5 * log2(e)
#define C2K   (36.067376022224086f)    // -2 * ZK

// Tiled layouts (MFMA-fragment order):
//   FT[(rt*5 + kc)*512 + l*8 + e]  = feat[rt*16 + (l&15)][kc*32 + (l>>4)*8 + e]
//   WTt[(tc*5 + kc)*512 + l*8 + e] = W[tc*16 + (l&15)][kc*32 + (l>>4)*8 + e]

// ---------------- ws layout (bytes) ----------------
#define FEAT_OFF  0ull
#define WT1_OFF   118437888ull
#define WT2_OFF   118483968ull      // contiguous after WT1 (46080 B each)
#define KERN2_OFF 118530048ull
#define WSUM_OFF  118534144ull
#define L3H_OFF   118534528ull
#define L4H_OFF   118538624ull
#define GSUM_OFF  118546816ull
#define GSQ_OFF   118547456ull

__device__ inline ushort f2h(float x) {
    return __builtin_bit_cast(ushort, (_Float16)x);
}
__device__ inline uint pack2h(float a, float b) {   // v_cvt_pkrtz_f16_f32
    return __builtin_bit_cast(uint, __builtin_amdgcn_cvt_pkrtz(a, b));
}

// ============ K0: all tables (91 blocks); W1/W2 in tiled order ============
__global__ void sdes_k0_setup(const float* __restrict__ conv_w, const float* __restrict__ l3w,
                              const float* __restrict__ l4w, const float* __restrict__ theta,
                              const float* __restrict__ phi, const float* __restrict__ c1w,
                              const float* __restrict__ c2w,
                              float* wsumT, ushort* l3h, ushort* l4h, float* kern2,
                              ushort* WT1t, ushort* WT2t, float* gsum, float* gsq)
{
    const int t = threadIdx.x, b = blockIdx.x;
    if (b == 90) {              // small tables
        for (int i = t; i < 96; i += 256) {
            int k = i >> 5, o = i & 31;
            wsumT[k * 32 + o] = conv_w[o * 6 + k] + conv_w[o * 6 + k + 3];
        }
        for (int i = t; i < 2048; i += 256) l3h[i] = f2h(l3w[i]);
        for (int i = t; i < 4096; i += 256) l4h[i] = f2h(l4w[i]);
        int m = t >> 2, bb = t & 3;
        float th = theta[m * 4 + bb], ph = phi[m * 4 + bb];
        float st = sinf(th), ct = cosf(th), sp = sinf(ph), cp = cosf(ph);
        kern2[m * 16 + bb * 4 + 0] = st * sp * C2K;
        kern2[m * 16 + bb * 4 + 1] = st * cp * C2K;
        kern2[m * 16 + bb * 4 + 2] = ct * C2K;
        kern2[m * 16 + bb * 4 + 3] = 0.f;
        return;
    }
    if (b == 0 && t < 160) { gsum[t] = 0.f; gsq[t] = 0.f; }
    int i = b * 256 + t;
    if (i >= 144 * 160) return;
    int e = i & 7, l = (i >> 3) & 63, rem = i >> 9;
    int kc = rem % 5, tc = rem / 5;
    int n = tc * 16 + (l & 15);
    int k = kc * 32 + (l >> 4) * 8 + e;
    float v = 0.f;
    if (n < 131) {
        if (k < 64)       v = c1w[n * 131 + 3 + k];
        else if (k < 128) v = c1w[n * 131 + 67 + (k - 64)];
        else if (k < 131) v = c1w[n * 131 + (k - 128)];
    }
    WT1t[i] = f2h(v);
    float v2 = (n < 131 && k < 131) ? c2w[n * 131 + k] : 0.f;
    WT2t[i] = f2h(v2);
}

// ============ K1ab: merged MLP (MFMA) + kernel-correlation -> tiled feat ============
// r13/r17 configuration (session best, 129.2 us): kern2 via lane-invariant s_load,
// z split 4 threads/point (512 thr), 16 resident waves/CU.
#define FST 40
#define W3T 40
#define W4T 72
__global__ __launch_bounds__(512) void sdes_k1ab(
    const float* __restrict__ corner, const float* __restrict__ conv_b,
    const float* __restrict__ wsumT, const ushort* __restrict__ l3h,
    const float* __restrict__ l3b, const ushort* __restrict__ l4h,
    const float* __restrict__ l4b,
    const float* __restrict__ normal, const int* __restrict__ neigh,
    const float* __restrict__ kern2g, ushort* __restrict__ feat)
{
    __shared__ __align__(16) ushort frcS[128 * FST];
    __shared__ __align__(16) ushort hS[128 * 64];
    __shared__ __align__(16) ushort w3S[64 * W3T];
    __shared__ __align__(16) ushort w4S[64 * W4T];
    __shared__ float wsL[96], cbL[32], b3L[64], b4L[64];
    const int t = threadIdx.x;

    // ---- stage k1a tables ----
    for (int i = t; i < 96; i += 512) wsL[i] = wsumT[i];
    for (int i = t; i < 32; i += 512) cbL[i] = conv_b[i];
    for (int i = t; i < 64; i += 512) { b3L[i] = l3b[i]; b4L[i] = l4b[i]; }
    for (int i = t; i < 256; i += 512) {
        int c = i >> 2, kc = i & 3;
        *(uint4*)&w3S[c * W3T + kc * 8] = *(const uint4*)&l3h[c * 32 + kc * 8];
    }
    for (int i = t; i < 512; i += 512) {
        int c = i >> 3, kc = i & 7;
        *(uint4*)&w4S[c * W4T + kc * 8] = *(const uint4*)&l4h[c * 64 + kc * 8];
    }
    __syncthreads();

    // ---- k1a per-point conv (threads 0..127) ----
    if (t < 128) {
        int row = blockIdx.x * 128 + t;
        int p = row < N_PTS ? row : N_PTS - 1;
        const float* cp = corner + (size_t)p * 9;
        float c0 = cp[0], c1 = cp[1], c2 = cp[2], c3 = cp[3], c4 = cp[4],
              c5 = cp[5], c6 = cp[6], c7 = cp[7], c8 = cp[8];
        float mp0 = (c0 + c3 + c6) * (1.f / 3.f);
        float mp1 = (c1 + c4 + c7) * (1.f / 3.f);
        float mp2 = (c2 + c5 + c8) * (1.f / 3.f);
        #pragma unroll
        for (int o = 0; o < 32; o += 2) {
            float f0 = fmaf(mp0, wsL[o], fmaf(mp1, wsL[32 + o], fmaf(mp2, wsL[64 + o], cbL[o])));
            float f1 = fmaf(mp0, wsL[o+1], fmaf(mp1, wsL[33 + o], fmaf(mp2, wsL[65 + o], cbL[o+1])));
            *(uint*)&frcS[t * FST + o] = pack2h(f0, f1);
        }
    }

    // ---- k1b body (all 512 threads, 4 threads/point; kern2 via s_load) ----
    {
        const int g  = t >> 7;                 // 0..3: (tt = g&1) m-half, (uu = g>>1) qq-half
        const int tt = g & 1;
        const int uu = g >> 1;
        const int pi = t & 127;
        const int p0 = blockIdx.x * 128 + pi;
        const int p = p0 < N_PTS ? p0 : N_PTS - 1;
        const int rt = p0 >> 4, pl = p0 & 15;
        float f0[4], f1[4], f2v[4];
        f0[0] = normal[(size_t)p * 3 + 0]; f1[0] = normal[(size_t)p * 3 + 1]; f2v[0] = normal[(size_t)p * 3 + 2];
        #pragma unroll
        for (int a = 1; a < 4; ++a) {
            int nb = neigh[(size_t)p * 3 + (a - 1)];
            f0[a] = normal[(size_t)nb * 3 + 0];
            f1[a] = normal[(size_t)nb * 3 + 1];
            f2v[a] = normal[(size_t)nb * 3 + 2];
        }
        float base[4];
        #pragma unroll
        for (int a = 0; a < 4; ++a)
            base[a] = (f0[a]*f0[a] + f1[a]*f1[a] + f2v[a]*f2v[a] + 1.0f) * ZK;
        const size_t tbase = ((size_t)(rt * 5 + 2 + tt)) * 512;
        #pragma unroll
        for (int qi = 0; qi < 2; ++qi) {
            const int qq = uu * 2 + qi;
            float zv[8];
            #pragma unroll
            for (int mm = 0; mm < 8; ++mm) {
                int m = (tt * 4 + qq) * 8 + mm;
                const float* kp = kern2g + m * 16;   // lane-invariant -> s_load (SGPR)
                float a0 = 0.f, a1 = 0.f, a2 = 0.f, a3 = 0.f;
                #pragma unroll
                for (int b = 0; b < 4; ++b) {
                    float kx = kp[b * 4 + 0], ky = kp[b * 4 + 1], kz = kp[b * 4 + 2];
                    a0 += __builtin_amdgcn_exp2f(fmaf(f0[0], kx, fmaf(f1[0], ky, fmaf(f2v[0], kz, base[0]))));
                    a1 += __builtin_amdgcn_exp2f(fmaf(f0[1], kx, fmaf(f1[1], ky, fmaf(f2v[1], kz, base[1]))));
                    a2 += __builtin_amdgcn_exp2f(fmaf(f0[2], kx, fmaf(f1[2], ky, fmaf(f2v[2], kz, base[2]))));
                    a3 += __builtin_amdgcn_exp2f(fmaf(f0[3], kx, fmaf(f1[3], ky, fmaf(f2v[3], kz, base[3]))));
                }
                zv[mm] = ((a0 + a1) + (a2 + a3)) * (1.f / 16.f);
            }
            uint4 v;
            v.x = pack2h(zv[0], zv[1]); v.y = pack2h(zv[2], zv[3]);
            v.z = pack2h(zv[4], zv[5]); v.w = pack2h(zv[6], zv[7]);
            *(uint4*)(feat + tbase + (pl + 16 * qq) * 8) = v;
        }
        {   // kc4 tile: row pl+16*g ; g==0 carries the normal, rest zeros
            size_t base4 = ((size_t)(rt * 5 + 4)) * 512;
            if (g == 0) {
                uint4 v;
                v.x = pack2h(f0[0], f1[0]); v.y = pack2h(f2v[0], 0.f); v.z = 0u; v.w = 0u;
                *(uint4*)(feat + base4 + pl * 8) = v;
            } else {
                const uint4 zz = {0u, 0u, 0u, 0u};
                *(uint4*)(feat + base4 + (pl + 16 * g) * 8) = zz;
            }
        }
    }
    __syncthreads();

    // ---- k1a MFMA layers (waves 0,1 only) ----
    const int lane = t & 63, w = t >> 6;
    const int rlo = lane & 15, kg = lane >> 4;
    const f32x4 z4 = {0.f, 0.f, 0.f, 0.f};

    if (w < 2) {   // layer 3: h[point][col] -> swizzled hS
        const int rbase = w * 64;
        half8 af[4], bf[4];
        #pragma unroll
        for (int rt = 0; rt < 4; ++rt)
            af[rt] = *(const half8*)&frcS[(rbase + rt * 16 + rlo) * FST + kg * 8];
        #pragma unroll
        for (int tc = 0; tc < 4; ++tc)
            bf[tc] = *(const half8*)&w3S[(tc * 16 + rlo) * W3T + kg * 8];
        #pragma unroll
        for (int rt = 0; rt < 4; ++rt) {
            #pragma unroll
            for (int tc = 0; tc < 4; ++tc) {
                f32x4 acc = __builtin_amdgcn_mfma_f32_16x16x32_f16(af[rt], bf[tc], z4, 0, 0, 0);
                int col = tc * 16 + rlo;
                float bias = b3L[col];
                #pragma unroll
                for (int r = 0; r < 4; ++r) {
                    int hrow = rbase + rt * 16 + kg * 4 + r;
                    float v = fmaxf(acc[r] + bias, 0.f);
                    int sc = (((col >> 3) ^ (hrow & 7)) << 3) | (col & 7);
                    hS[hrow * 64 + sc] = f2h(v);
                }
            }
        }
    }
    __syncthreads();

    if (w < 2) {   // layer 4 SWAPPED: acc = mfma(W4_frag, h_frag) -> D[xcol][point]
        const int rbase = w * 64;
        f32x4 acc4[4][4];
        #pragma unroll
        for (int pt = 0; pt < 4; ++pt)
            #pragma unroll
            for (int tc = 0; tc < 4; ++tc) acc4[pt][tc] = z4;
        #pragma unroll
        for (int ks = 0; ks < 2; ++ks) {
            half8 af[4], bf[4];
            #pragma unroll
            for (int pt = 0; pt < 4; ++pt) {
                int row = rbase + pt * 16 + rlo;
                int blk = (ks * 4 + kg) ^ (rlo & 7);
                af[pt] = *(const half8*)&hS[row * 64 + blk * 8];
            }
            #pragma unroll
            for (int tc = 0; tc < 4; ++tc)
                bf[tc] = *(const half8*)&w4S[(tc * 16 + rlo) * W4T + ks * 32 + kg * 8];
            #pragma unroll
            for (int pt = 0; pt < 4; ++pt)
                #pragma unroll
                for (int tc = 0; tc < 4; ++tc)
                    acc4[pt][tc] = __builtin_amdgcn_mfma_f32_16x16x32_f16(bf[tc], af[pt], acc4[pt][tc], 0, 0, 0);
        }
        #pragma unroll
        for (int pt = 0; pt < 4; ++pt) {
            int rtg = blockIdx.x * 8 + w * 4 + pt;
            #pragma unroll
            for (int tc = 0; tc < 4; ++tc) {
                int xb = tc * 16 + kg * 4;
                float v0 = acc4[pt][tc][0] + b4L[xb + 0];
                float v1 = acc4[pt][tc][1] + b4L[xb + 1];
                float v2 = acc4[pt][tc][2] + b4L[xb + 2];
                float v3 = acc4[pt][tc][3] + b4L[xb + 3];
                uint2v st; st.x = pack2h(v0, v1); st.y = pack2h(v2, v3);
                int kc = tc >> 1;
                int l = rlo + 16 * ((2 * tc + (kg >> 1)) & 3);
                size_t off = ((size_t)(rtg * 5 + kc)) * 512 + l * 8 + (kg & 1) * 4;
                *(uint2v*)(feat + off) = st;
            }
        }
    }
}

// ============ K2s: PERSISTENT stats GEMM1; 256 blocks x 1024 thr (16 waves, 4/SIMD) ====
__global__ __launch_bounds__(1024, 4) void sdes_k2_stats(
    const ushort* __restrict__ FT, const ushort* __restrict__ WT1t,
    const float* __restrict__ c1b, float* __restrict__ gsum, float* __restrict__ gsq)
{
    __shared__ __align__(16) ushort W1s[45 * 512];     // 46080 B
    __shared__ float sS[144], sQ[144];
    const int t = threadIdx.x;
    const int lane = t & 63, wv = t >> 6;
    const int b = blockIdx.x;
    const int s = b * 16 + wv;                         // 4096 slots
    const int rlo = lane & 15, kg = lane >> 4;

    // balanced contiguous tile range: 12504 = 4096*3 + 216
    const int cnt = 3 + ((wv == 0 && b < 216) ? 1 : 0);
    const int start = 3 * s + (b < 216 ? b : 216) + ((b < 216 && wv > 0) ? 1 : 0);

    // first-tile FT prefetch (rides under the W1 staging)
    half8 afA[5], afB[5];
    #pragma unroll
    for (int kc = 0; kc < 5; ++kc)
        afA[kc] = *(const half8*)(FT + ((size_t)start * 5 + kc) * 512 + lane * 8);

    for (int i = t; i < 2880; i += 1024) ((uint4*)W1s)[i] = ((const uint4*)WT1t)[i];
    if (t < 144) { sS[t] = 0.f; sQ[t] = 0.f; }
    __syncthreads();

    float sreg[9], qreg[9], bL[9];
    #pragma unroll
    for (int tc = 0; tc < 9; ++tc) {
        sreg[tc] = 0.f; qreg[tc] = 0.f;
        int n = tc * 16 + rlo;
        bL[tc] = (n < 131) ? c1b[n] : 0.f;
    }

    for (int it = 0; it < cnt; ++it) {
        const int p = start + it;
        f32x4 acc[9];
        #pragma unroll
        for (int tc = 0; tc < 9; ++tc) acc[tc] = (f32x4){0.f, 0.f, 0.f, 0.f};
        #pragma unroll
        for (int kc = 0; kc < 5; ++kc) {
            #pragma unroll
            for (int tc = 0; tc < 9; ++tc) {
                half8 bw = *(const half8*)(W1s + (tc * 5 + kc) * 512 + lane * 8);
                acc[tc] = __builtin_amdgcn_mfma_f32_16x16x32_f16(afA[kc], bw, acc[tc], 0, 0, 0);
            }
        }
        if (it + 1 < cnt) {
            #pragma unroll
            for (int kc = 0; kc < 5; ++kc)
                afB[kc] = *(const half8*)(FT + ((size_t)(p + 1) * 5 + kc) * 512 + lane * 8);
            __builtin_amdgcn_sched_barrier(0);   // pin prefetch issue here
        }
        const int row0 = p * 16;
        #pragma unroll
        for (int tc = 0; tc < 9; ++tc) {
            float b0 = bL[tc];
            #pragma unroll
            for (int r = 0; r < 4; ++r) {
                int grow = row0 + kg * 4 + r;
                if (grow < N_PTS) {
                    float v = acc[tc][r] + b0;
                    sreg[tc] += v;
                    qreg[tc] = fmaf(v, v, qreg[tc]);
                }
            }
        }
        #pragma unroll
        for (int kc = 0; kc < 5; ++kc) afA[kc] = afB[kc];
    }

    #pragma unroll
    for (int tc = 0; tc < 9; ++tc) {
        float sv = sreg[tc], qv = qreg[tc];
        sv += __shfl_xor(sv, 16);  sv += __shfl_xor(sv, 32);
        qv += __shfl_xor(qv, 16);  qv += __shfl_xor(qv, 32);
        if (lane < 16) {
            int n = tc * 16 + rlo;
            atomicAdd(&sS[n], sv); atomicAdd(&sQ[n], qv);
        }
    }
    __syncthreads();
    if (t < 144) { atomicAdd(&gsum[t], sS[t]); atomicAdd(&gsq[t], sQ[t]); }
}

// ============ K3f: PERSISTENT fused GEMM1 -> bn/relu -> slab -> GEMM2 ============
// 256 blocks x 768 threads (12 waves, 3/SIMD). Ws staged + BN finalized ONCE per
// block; balanced contiguous pair ranges; double-buffered FT prefetch.
// Phase B SWAPPED (D[chan][point]) -> lane owns 4 CONSECUTIVE chans of one row
// -> single cached float4 store per tc (wave covers 16 rows x 64B full segments).
__global__ __launch_bounds__(768, 3) void sdes_k3_fused(
    const ushort* __restrict__ FT, const ushort* __restrict__ WT1t,
    const ushort* __restrict__ WT2t, const float* __restrict__ c1b,
    const float* __restrict__ gsum, const float* __restrict__ gsq,
    const float* __restrict__ bng, const float* __restrict__ bnb,
    const float* __restrict__ c2b, float* __restrict__ out)
{
    __shared__ __align__(16) ushort Ws[2 * 45 * 512];   // 92160 B: W1 [0..23039], W2 [23040..]
    __shared__ __align__(16) ushort yS[192 * YST];      // 12 waves x 16 rows x 168 = 64512 B
    __shared__ __align__(16) float scL[160], shL[160], b1L[160], c2L[160];
    const int t = threadIdx.x;
    const int lane = t & 63, wv = t >> 6;
    const int rlo = lane & 15, kg = lane >> 4;
    const int b = blockIdx.x;
    const int s = b * 12 + wv;                          // 3072 slots

    // balanced contiguous pair range: 6252 = 3072*2 + 108 (extra -> wv0 of b<108)
    const int cnt = 2 + ((wv == 0 && b < 108) ? 1 : 0);
    const int start = 2 * s + (b < 108 ? b : 108) + ((b < 108 && wv > 0) ? 1 : 0);

    // ---- first-pair FT prefetch, issued BEFORE staging (rides under L2 staging) ----
    half8 afA[5][2], afB[5][2];
    #pragma unroll
    for (int kc = 0; kc < 5; ++kc)
        #pragma unroll
        for (int pt = 0; pt < 2; ++pt)
            afA[kc][pt] = *(const half8*)(FT + ((size_t)(start * 2 + pt) * 5 + kc) * 512 + lane * 8);

    // ---- stage both weight matrices into LDS (92 KB, ONCE per block) ----
    for (int i = t; i < 5760; i += 768) ((uint4*)Ws)[i] = ((const uint4*)WT1t)[i];

    // ---- BN finalize (once per block, 131 lanes) ----
    if (t < 160) {
        float sc = 0.f, sh = 0.f, bb = 0.f, c2 = 0.f;
        if (t < 131) {
            float mu = gsum[t] * (1.f / 200000.f);
            float var = gsq[t] * (1.f / 200000.f) - mu * mu;
            sc = bng[t] / sqrtf(var + 1e-5f);
            sh = bnb[t] - mu * sc;
            bb = c1b[t]; c2 = c2b[t];
        }
        scL[t] = sc; shL[t] = sh; b1L[t] = bb; c2L[t] = c2;
    }
    __syncthreads();

    const half8 hz = {0, 0, 0, 0, 0, 0, 0, 0};
    ushort* slab = yS + wv * 16 * YST;      // this wave's 16-row slab (reused per pt/iter)

    for (int it = 0; it < cnt; ++it) {
        const int p = start + it;

        // ---- Phase A: y = feat @ W1^T (D[point][chan]); W1 from LDS ----
        f32x4 acc[2][9];
        #pragma unroll
        for (int pt = 0; pt < 2; ++pt)
            #pragma unroll
            for (int tc = 0; tc < 9; ++tc) acc[pt][tc] = (f32x4){0.f, 0.f, 0.f, 0.f};
        #pragma unroll
        for (int kc = 0; kc < 5; ++kc) {
            #pragma unroll
            for (int tc = 0; tc < 9; ++tc) {
                half8 bw = *(const half8*)(Ws + (tc * 5 + kc) * 512 + lane * 8);
                #pragma unroll
                for (int pt = 0; pt < 2; ++pt)
                    acc[pt][tc] = __builtin_amdgcn_mfma_f32_16x16x32_f16(afA[kc][pt], bw, acc[pt][tc], 0, 0, 0);
            }
        }

        // ---- prefetch next pair's FT fragments (pinned; hides under phase B) ----
        if (it + 1 < cnt) {
            #pragma unroll
            for (int kc = 0; kc < 5; ++kc)
                #pragma unroll
                for (int pt = 0; pt < 2; ++pt)
                    afB[kc][pt] = *(const half8*)(FT + ((size_t)((p + 1) * 2 + pt) * 5 + kc) * 512 + lane * 8);
            __builtin_amdgcn_sched_barrier(0);
        }

        const int row0 = p * 32;
        #pragma unroll
        for (int pt = 0; pt < 2; ++pt) {
            // ---- bias + bn + relu -> slab (16 rows x 144 chans; chans>=131 exact 0) ----
            #pragma unroll
            for (int tc = 0; tc < 9; ++tc) {
                int n = tc * 16 + rlo;
                float sc = scL[n], sh = shL[n], bb = b1L[n];
                #pragma unroll
                for (int r = 0; r < 4; ++r) {
                    float v = fmaxf(fmaf(acc[pt][tc][r] + bb, sc, sh), 0.f);
                    slab[(kg * 4 + r) * YST + n] = f2h(v);
                }
            }
            // same-wave DS ordering: reads below see this pt's writes.

            // ---- Phase B SWAPPED: out = y_relu @ W2^T, D[chan][point] ----
            f32x4 acc2[9];
            #pragma unroll
            for (int tc = 0; tc < 9; ++tc) acc2[tc] = (f32x4){0.f, 0.f, 0.f, 0.f};
            #pragma unroll
            for (int kc2 = 0; kc2 < 5; ++kc2) {
                bool vld = (kc2 < 4) || (kg < 2);
                half8 af2 = vld ? *(const half8*)&slab[rlo * YST + kc2 * 32 + kg * 8] : hz;
                #pragma unroll
                for (int tc = 0; tc < 9; ++tc) {
                    half8 bw = *(const half8*)(Ws + 23040 + (tc * 5 + kc2) * 512 + lane * 8);
                    acc2[tc] = __builtin_amdgcn_mfma_f32_16x16x32_f16(bw, af2, acc2[tc], 0, 0, 0);
                }
            }
            // ---- epilogue: lane owns point=row0+pt*16+rlo, chans tc*16+kg*4+0..3
            //      single cached float4 store per tc (4B-aligned rows OK on gfx950) ----
            const int prow = row0 + pt * 16 + rlo;
            if (prow < N_PTS) {
                float* op = out + (size_t)prow * 131;
                #pragma unroll
                for (int tc = 0; tc < 8; ++tc) {
                    const int c0 = tc * 16 + kg * 4;
                    f32x4 vv = acc2[tc] + *(const f32x4*)&c2L[c0];
                    __builtin_memcpy(op + c0, &vv, 16);   // global_store_dwordx4, align 4
                }
                if (kg == 0) {   // chans 128..130
                    op[128] = acc2[8][0] + c2L[128];
                    op[129] = acc2[8][1] + c2L[129];
                    op[130] = acc2[8][2] + c2L[130];
                }
            }
        }

        // ---- rotate double buffer ----
        #pragma unroll
        for (int kc = 0; kc < 5; ++kc)
            #pragma unroll
            for (int pt = 0; pt < 2; ++pt)
                afA[kc][pt] = afB[kc][pt];
    }
}

extern "C" void kernel_launch(void* const* d_in, const int* in_sizes, int n_in,
                              void* d_out, int out_size, void* d_ws, size_t ws_size,
                              hipStream_t stream) {
    const float* corner = (const float*)d_in[0];
    const float* normal = (const float*)d_in[1];
    const int*   neigh  = (const int*)d_in[2];
    const float* conv_w = (const float*)d_in[3];
    const float* conv_b = (const float*)d_in[4];
    const float* l3_w   = (const float*)d_in[5];
    const float* l3_b   = (const float*)d_in[6];
    const float* l4_w   = (const float*)d_in[7];
    const float* l4_b   = (const float*)d_in[8];
    const float* theta  = (const float*)d_in[9];
    const float* phi    = (const float*)d_in[10];
    const float* c1_w   = (const float*)d_in[11];
    const float* c1_b   = (const float*)d_in[12];
    const float* c2_w   = (const float*)d_in[13];
    const float* c2_b   = (const float*)d_in[14];
    const float* bn_g   = (const float*)d_in[15];
    const float* bn_b   = (const float*)d_in[16];

    char* ws = (char*)d_ws;
    ushort* feat  = (ushort*)(ws + FEAT_OFF);
    ushort* WT1t  = (ushort*)(ws + WT1_OFF);
    ushort* WT2t  = (ushort*)(ws + WT2_OFF);
    float*  kern2 = (float*)(ws + KERN2_OFF);
    float*  wsumT = (float*)(ws + WSUM_OFF);
    ushort* l3h   = (ushort*)(ws + L3H_OFF);
    ushort* l4h   = (ushort*)(ws + L4H_OFF);
    float*  gsum  = (float*)(ws + GSUM_OFF);
    float*  gsq   = (float*)(ws + GSQ_OFF);

    sdes_k0_setup<<<91, 256, 0, stream>>>(conv_w, l3_w, l4_w, theta, phi, c1_w, c2_w,
                                          wsumT, l3h, l4h, kern2, WT1t, WT2t, gsum, gsq);
    sdes_k1ab<<<NBLK, 512, 0, stream>>>(corner, conv_b, wsumT, l3h, l3_b, l4h, l4_b,
                                        normal, neigh, kern2, feat);
    sdes_k2_stats<<<256, 1024, 0, stream>>>(feat, WT1t, c1_b, gsum, gsq);
    sdes_k3_fused<<<256, 768, 0, stream>>>(feat, WT1t, WT2t, c1_b, gsum, gsq,
                                           bn_g, bn_b, c2_b, (float*)d_out);
}